// Round 5
// baseline (1096.505 us; speedup 1.0000x reference)
//
#include <hip/hip_runtime.h>
#include <hip/hip_bf16.h>

#define NN 50000
#define NE_MAIN 800000
#define NE_CONT 200000
#define NP 50176        // padded histogram size (>= NN)
#define BLK_M 768       // main edge blocks (%8==0)
#define BLK_C 192       // cont edge blocks (%8==0)

typedef __attribute__((ext_vector_type(8))) short bf8;   // 8 x bf16 (4 VGPRs)
typedef __attribute__((ext_vector_type(4))) float f4;    // 4 x f32

static __device__ __forceinline__ float bf2f(short s) {
  return __builtin_bit_cast(float, ((unsigned int)(unsigned short)s) << 16);
}
static __device__ __forceinline__ short f2bf(float f) {
  __hip_bfloat16 h = __float2bfloat16(f);   // RNE; compiler can pack v_cvt_pk_bf16_f32
  return __builtin_bit_cast(short, h);
}

// ---------------------------------------------------------------- zero ----
__global__ __launch_bounds__(256) void zero_kernel(f4* __restrict__ p, int n4) {
  int i = blockIdx.x * 256 + threadIdx.x;
  int stride = gridDim.x * 256;
  f4 z = {0.f, 0.f, 0.f, 0.f};
  for (; i < n4; i += stride) p[i] = z;
}

// ------------------------------------------------- counting sort by j ----
__global__ __launch_bounds__(256) void hist_kernel(const int* __restrict__ idx, int nE,
                                                   int* __restrict__ hist) {
  int e = blockIdx.x * 256 + threadIdx.x;
  int st = gridDim.x * 256;
  for (; e < nE; e += st) atomicAdd(&hist[idx[nE + e]], 1);
}

__global__ __launch_bounds__(512) void scan1_kernel(const int* __restrict__ hist,
                                                    int* __restrict__ cursor,
                                                    int* __restrict__ tsums, int n) {
  __shared__ int buf[2][512];
  int tid = threadIdx.x;
  int i = blockIdx.x * 512 + tid;
  int v = (i < n) ? hist[i] : 0;
  int cur = 0;
  buf[0][tid] = v;
  __syncthreads();
#pragma unroll
  for (int off = 1; off < 512; off <<= 1) {
    int t = buf[cur][tid];
    if (tid >= off) t += buf[cur][tid - off];
    buf[cur ^ 1][tid] = t;
    cur ^= 1;
    __syncthreads();
  }
  int incl = buf[cur][tid];
  if (i < n) cursor[i] = incl - v;
  if (tid == 511) tsums[blockIdx.x] = incl;
}

__global__ __launch_bounds__(512) void scan2_kernel(int* __restrict__ tsums, int nt) {
  __shared__ int buf[2][512];
  int tid = threadIdx.x;
  int v = (tid < nt) ? tsums[tid] : 0;
  int cur = 0;
  buf[0][tid] = v;
  __syncthreads();
#pragma unroll
  for (int off = 1; off < 512; off <<= 1) {
    int t = buf[cur][tid];
    if (tid >= off) t += buf[cur][tid - off];
    buf[cur ^ 1][tid] = t;
    cur ^= 1;
    __syncthreads();
  }
  if (tid < nt) tsums[tid] = buf[cur][tid] - v;
}

__global__ __launch_bounds__(512) void scan3_kernel(int* __restrict__ cursor,
                                                    const int* __restrict__ tsums, int n) {
  int i = blockIdx.x * 512 + threadIdx.x;
  if (i < n) cursor[i] += tsums[blockIdx.x];
}

__global__ __launch_bounds__(256) void scatter_kernel(const int* __restrict__ idx, int nE,
                                                      int* __restrict__ cursor,
                                                      int* __restrict__ si, int* __restrict__ sj) {
  int e = blockIdx.x * 256 + threadIdx.x;
  int st = gridDim.x * 256;
  for (; e < nE; e += st) {
    int i = idx[e], j = idx[nE + e];
    int p = atomicAdd(&cursor[j], 1);
    si[p] = i;
    sj[p] = j;
  }
}

// --------------------------------------------------- weight transpose ----
struct WTDesc {
  const float* src[11];
  int K[11];
  int off[11];
};
__global__ __launch_bounds__(128) void wt_kernel(WTDesc d, short* __restrict__ dst) {
  int m = blockIdx.x >> 7;
  int n = blockIdx.x & 127;
  const float* s = d.src[m];
  int K = d.K[m];
  short* o = dst + d.off[m] + (size_t)n * K;
  for (int k = threadIdx.x; k < K; k += 128) o[k] = f2bf(s[(size_t)k * 128 + n]);
}

// ------------------------------------------------------- MFMA helpers ----
// 64-row tile in LDS (bf16, 16B-chunk XOR swizzle: chunk ^= row&7).
// A-frag: row = lane&15 (+rf*16), k = (lane>>4)*8 + j (+ks*32)
// B-frag: col = lane&15 (+cf*16), same k pattern, from WT[N][K].
// C/D  : col = lane&15, row = (lane>>4)*4 + reg  [HW-verified]
template <int K>
static __device__ __forceinline__ void mfma_gemm(const short* __restrict__ sA, int rs16,
                                                 const short* __restrict__ WT,
                                                 int c0, int lane,
                                                 const float* __restrict__ bias,
                                                 f4 (&acc)[4][2]) {
  const int colA = c0 + (lane & 15);
  const int colB = colA + 16;
  if (bias) {
    float ba = bias[colA], bb = bias[colB];
#pragma unroll
    for (int rf = 0; rf < 4; ++rf) {
      acc[rf][0] = (f4){ba, ba, ba, ba};
      acc[rf][1] = (f4){bb, bb, bb, bb};
    }
  } else {
#pragma unroll
    for (int rf = 0; rf < 4; ++rf) {
      acc[rf][0] = (f4){0.f, 0.f, 0.f, 0.f};
      acc[rf][1] = (f4){0.f, 0.f, 0.f, 0.f};
    }
  }
  const int g = lane >> 4;
  const int rowl = lane & 15;
#pragma unroll 4
  for (int ks = 0; ks < (K >> 5); ++ks) {
    bf8 b0 = *reinterpret_cast<const bf8*>(WT + (size_t)colA * K + ks * 32 + g * 8);
    bf8 b1 = *reinterpret_cast<const bf8*>(WT + (size_t)colB * K + ks * 32 + g * 8);
    int chunk = ks * 4 + g;
#pragma unroll
    for (int rf = 0; rf < 4; ++rf) {
      int row = rf * 16 + rowl;
      bf8 a = *reinterpret_cast<const bf8*>(sA + row * rs16 * 8 + ((chunk ^ (row & 7)) << 3));
      acc[rf][0] = __builtin_amdgcn_mfma_f32_16x16x32_bf16(a, b0, acc[rf][0], 0, 0, 0);
      acc[rf][1] = __builtin_amdgcn_mfma_f32_16x16x32_bf16(a, b1, acc[rf][1], 0, 0, 0);
    }
  }
}

template <bool RELU, bool SWZ>
static __device__ __forceinline__ void store_frags(short* __restrict__ dst, int rs16,
                                                   int c0, int lane, const f4 (&acc)[4][2]) {
#pragma unroll
  for (int rf = 0; rf < 4; ++rf)
#pragma unroll
    for (int q = 0; q < 4; ++q) {
      int row = rf * 16 + ((lane >> 4) << 2) + q;
#pragma unroll
      for (int cf = 0; cf < 2; ++cf) {
        int col = c0 + cf * 16 + (lane & 15);
        float v = acc[rf][cf][q];
        if (RELU) v = fmaxf(v, 0.f);
        int idx;
        if (SWZ) idx = row * rs16 * 8 + (((col >> 3) ^ (row & 7)) << 3) + (col & 7);
        else     idx = row * rs16 * 8 + col;
        dst[idx] = f2bf(v);
      }
    }
}

// per-row sum/sumsq over this wave's 32 cols -> sP[wave*64+row]
static __device__ __forceinline__ void ln_rows(const f4 (&acc)[4][2], int lane, int wave,
                                               float2* __restrict__ sP) {
#pragma unroll
  for (int rf = 0; rf < 4; ++rf)
#pragma unroll
    for (int q = 0; q < 4; ++q) {
      float v0 = acc[rf][0][q], v1 = acc[rf][1][q];
      float s = v0 + v1;
      float qq = v0 * v0 + v1 * v1;
      s += __shfl_xor(s, 1);  qq += __shfl_xor(qq, 1);
      s += __shfl_xor(s, 2);  qq += __shfl_xor(qq, 2);
      s += __shfl_xor(s, 4);  qq += __shfl_xor(qq, 4);
      s += __shfl_xor(s, 8);  qq += __shfl_xor(qq, 8);
      if ((lane & 15) == 0) {
        int row = rf * 16 + ((lane >> 4) << 2) + q;
        sP[wave * 64 + row] = make_float2(s, qq);
      }
    }
}

// ------------------------------------------------------------ precompute ----
// xa tables = x@W0_i-slice; xb tables = x@W0_j-slice + b0 (bias folded here).
__global__ __launch_bounds__(256) void precompute_kernel(
    const float* __restrict__ x, const short* __restrict__ WTp,
    const float* __restrict__ mb0, const float* __restrict__ cb0,
    short* __restrict__ xa_m, short* __restrict__ xb_m,
    short* __restrict__ xa_c, short* __restrict__ xb_c) {
  __shared__ __align__(16) short sA[64 * 128];
  __shared__ __align__(16) short sOut[64 * 128];
  const int tid = threadIdx.x;
  const int lane = tid & 63, wave = tid >> 6;
  const int c0 = wave * 32;
  const int n0 = blockIdx.x * 64;

#pragma unroll
  for (int it = 0; it < 4; ++it) {
    int s = it * 256 + tid;
    int e = s >> 4, c = s & 15;
    int n = n0 + e;
    f4 u0 = {0.f, 0.f, 0.f, 0.f}, u1 = {0.f, 0.f, 0.f, 0.f};
    if (n < NN) {
      u0 = *reinterpret_cast<const f4*>(x + (size_t)n * 128 + c * 8);
      u1 = *reinterpret_cast<const f4*>(x + (size_t)n * 128 + c * 8 + 4);
    }
    bf8 o;
#pragma unroll
    for (int j = 0; j < 4; ++j) { o[j] = f2bf(u0[j]); o[j + 4] = f2bf(u1[j]); }
    *reinterpret_cast<bf8*>(sA + e * 128 + ((c ^ (e & 7)) << 3)) = o;
  }
  __syncthreads();

  short* dsts[4] = {xa_m, xb_m, xa_c, xb_c};
  const float* biases[4] = {nullptr, mb0, nullptr, cb0};
#pragma unroll 1
  for (int o = 0; o < 4; ++o) {
    f4 acc[4][2];
    mfma_gemm<128>(sA, 16, WTp + o * 16384, c0, lane, biases[o], acc);
    store_frags<false, false>(sOut, 16, c0, lane, acc);
    __syncthreads();
    short* dst = dsts[o];
#pragma unroll
    for (int it = 0; it < 4; ++it) {
      int s = it * 256 + tid;
      int e = s >> 4, c = s & 15;
      int n = n0 + e;
      if (n < NN)
        *reinterpret_cast<bf8*>(dst + (size_t)n * 128 + c * 8) =
            *reinterpret_cast<const bf8*>(sOut + e * 128 + c * 8);
    }
    __syncthreads();
  }
}

// ------------------------------------------------------- fused edge MLP ----
struct EdgeArgs {
  const int* si; const int* sj;
  const short* xa; const short* xb;
  const float* pp;
  const float* W0f;
  const short* WT1; const float* b1;
  const short* WT2; const float* b2;
  float* agg;
  int ntiles; int nblocks; int nf;
};

template <int NF>
static __device__ __forceinline__ void stage_h0(short* __restrict__ sA,
                                                const bf8 (&pxa)[4], const bf8 (&pxb)[4],
                                                const float (* __restrict__ sFc)[8],
                                                const float* __restrict__ W0f, int tid) {
#pragma unroll
  for (int it = 0; it < 4; ++it) {
    int s = it * 256 + tid;
    int e = s >> 4, c = s & 15;
    float h[8];
#pragma unroll
    for (int jj = 0; jj < 8; ++jj) h[jj] = bf2f(pxa[it][jj]) + bf2f(pxb[it][jj]);
#pragma unroll
    for (int q = 0; q < NF; ++q) {
      float fq = sFc[e][q];
      f4 w0 = *reinterpret_cast<const f4*>(W0f + q * 128 + c * 8);
      f4 w1 = *reinterpret_cast<const f4*>(W0f + q * 128 + c * 8 + 4);
#pragma unroll
      for (int jj = 0; jj < 4; ++jj) {
        h[jj]     = fmaf(fq, w0[jj], h[jj]);
        h[jj + 4] = fmaf(fq, w1[jj], h[jj + 4]);
      }
    }
    bf8 o;
#pragma unroll
    for (int jj = 0; jj < 8; ++jj) o[jj] = f2bf(fmaxf(h[jj], 0.f));
    *reinterpret_cast<bf8*>(sA + e * 128 + ((c ^ (e & 7)) << 3)) = o;
  }
}

// Persistent chunked blocks; edges sorted by j; 2-deep pipeline:
//   loop: [issue idx(t+1)] h0(t) | barA | [feats(t+1)->LDS] GEMM1 | barB |
//         [issue xa/xb gather(t+1)->regs] GEMM2 LN | ... | reduce+atomics | barF
__global__ __launch_bounds__(256, 4) void edge_fused_kernel(EdgeArgs am, EdgeArgs ac,
                                                            int blocks_m) {
  __shared__ __align__(16) short sAB[2 * 64 * 128];   // h0 | h1, reused as f32 T tile
  __shared__ int sI[2][64], sJ[2][64];
  __shared__ float sF[2][64][8];
  __shared__ float2 sP[4 * 64];
  __shared__ float2 sStats[64];
  const int tid = threadIdx.x;
  const int lane = tid & 63, wave = tid >> 6;
  const int c0 = wave * 32;
  short* sA = sAB;
  short* sB = sAB + 64 * 128;
  float* sT = reinterpret_cast<float*>(sAB);

  EdgeArgs A;
  int lb;
  if ((int)blockIdx.x < blocks_m) { A = am; lb = blockIdx.x; }
  else                            { A = ac; lb = blockIdx.x - blocks_m; }
  // XCD-contiguous remap (nblocks % 8 == 0): each XCD owns a contiguous j-range
  const int per = A.nblocks >> 3;
  lb = (lb & 7) * per + (lb >> 3);
  // contiguous tile chunk for this block
  const int q = A.ntiles / A.nblocks, r = A.ntiles % A.nblocks;
  const int t0 = lb * q + (lb < r ? lb : r);
  const int t1 = t0 + q + (lb < r ? 1 : 0);
  if (t0 >= t1) return;
  const int nf = A.nf;

  // ---- prologue: idx/pos/feats for tile t0, then issue its gather ----
  int cur = 0;
  if (tid < 64) {
    int e = t0 * 64 + tid;
    int i = A.si[e], j = A.sj[e];
    sI[0][tid] = i; sJ[0][tid] = j;
    const float* pi = A.pp + (size_t)i * 6;
    const float* pj = A.pp + (size_t)j * 6;
    float d0 = pi[0] - pj[0], d1 = pi[1] - pj[1], d2 = pi[2] - pj[2];
    float w0 = pi[3] - pj[3], w1 = pi[4] - pj[4], w2 = pi[5] - pj[5];
    float* sf = sF[0][tid];
    if (nf == 8) {
      sf[0] = d0; sf[1] = d1; sf[2] = d2; sf[3] = sqrtf(d0 * d0 + d1 * d1 + d2 * d2);
      sf[4] = w0; sf[5] = w1; sf[6] = w2; sf[7] = sqrtf(w0 * w0 + w1 * w1 + w2 * w2);
    } else {
      sf[0] = w0; sf[1] = w1; sf[2] = w2; sf[3] = sqrtf(w0 * w0 + w1 * w1 + w2 * w2);
    }
  }
  __syncthreads();

  bf8 pxa[4], pxb[4];
#pragma unroll
  for (int it = 0; it < 4; ++it) {
    int s = it * 256 + tid, e = s >> 4, c = s & 15;
    pxa[it] = *reinterpret_cast<const bf8*>(A.xa + (size_t)sI[0][e] * 128 + c * 8);
    pxb[it] = *reinterpret_cast<const bf8*>(A.xb + (size_t)sJ[0][e] * 128 + c * 8);
  }

  for (int tt = t0; tt < t1; ++tt) {
    const bool nb = (tt + 1 < t1);
    // (1) issue next-tile idx loads only (latency hides under h0 staging)
    int ni = 0, nj2 = 0;
    if (nb && tid < 64) {
      int e = (tt + 1) * 64 + tid;
      ni = A.si[e];
      nj2 = A.sj[e];
    }
    // (2) h0 staging from prefetched regs
    if (nf == 8) stage_h0<8>(sA, pxa, pxb, sF[cur], A.W0f, tid);
    else         stage_h0<4>(sA, pxa, pxb, sF[cur], A.W0f, tid);
    __syncthreads();                                   // A: h0 visible
    // (4) next-tile pos gather + feats -> LDS (overlaps GEMM1 on other waves)
    if (nb && tid < 64) {
      int nxt = cur ^ 1;
      sI[nxt][tid] = ni; sJ[nxt][tid] = nj2;
      const float* pi = A.pp + (size_t)ni * 6;
      const float* pj = A.pp + (size_t)nj2 * 6;
      float d0 = pi[0] - pj[0], d1 = pi[1] - pj[1], d2 = pi[2] - pj[2];
      float w0 = pi[3] - pj[3], w1 = pi[4] - pj[4], w2 = pi[5] - pj[5];
      float* sf = sF[nxt][tid];
      if (nf == 8) {
        sf[0] = d0; sf[1] = d1; sf[2] = d2; sf[3] = sqrtf(d0 * d0 + d1 * d1 + d2 * d2);
        sf[4] = w0; sf[5] = w1; sf[6] = w2; sf[7] = sqrtf(w0 * w0 + w1 * w1 + w2 * w2);
      } else {
        sf[0] = w0; sf[1] = w1; sf[2] = w2; sf[3] = sqrtf(w0 * w0 + w1 * w1 + w2 * w2);
      }
    }
    f4 acc[4][2];
    mfma_gemm<128>(sA, 16, A.WT1, c0, lane, A.b1, acc);   // h1 = relu(h0)@W1+b1
    store_frags<true, true>(sB, 16, c0, lane, acc);
    __syncthreads();                                   // B: h1 + sI[nxt] visible
    // (8) issue next-tile xa/xb gather -> regs; hides under GEMM2+LN+reduce
    if (nb) {
      int nxt = cur ^ 1;
#pragma unroll
      for (int it = 0; it < 4; ++it) {
        int s = it * 256 + tid, e = s >> 4, c = s & 15;
        pxa[it] = *reinterpret_cast<const bf8*>(A.xa + (size_t)sI[nxt][e] * 128 + c * 8);
        pxb[it] = *reinterpret_cast<const bf8*>(A.xb + (size_t)sJ[nxt][e] * 128 + c * 8);
      }
    }
    mfma_gemm<128>(sB, 16, A.WT2, c0, lane, A.b2, acc);   // h2 = relu(h1)@W2+b2
    ln_rows(acc, lane, wave, sP);
    __syncthreads();                                   // C
    if (tid < 64) {
      float s = 0.f, qq = 0.f;
#pragma unroll
      for (int w = 0; w < 4; ++w) { s += sP[w * 64 + tid].x; qq += sP[w * 64 + tid].y; }
      float mean = s * (1.f / 128.f);
      float var = qq * (1.f / 128.f) - mean * mean;
      sStats[tid] = make_float2(mean, rsqrtf(var + 1e-5f));
    }
    __syncthreads();                                   // D
    // normalized h2 -> f32 T tile (bank-rotated: (col+4*row)&127 -> conflict-free)
#pragma unroll
    for (int rf = 0; rf < 4; ++rf)
#pragma unroll
      for (int qq2 = 0; qq2 < 4; ++qq2) {
        int row = rf * 16 + ((lane >> 4) << 2) + qq2;
        float mean = sStats[row].x, rn = sStats[row].y;
#pragma unroll
        for (int cf = 0; cf < 2; ++cf) {
          int col = c0 + cf * 16 + (lane & 15);
          sT[row * 128 + ((col + 4 * row) & 127)] = (acc[rf][cf][qq2] - mean) * rn;
        }
      }
    __syncthreads();                                   // E
    // segmented column sums: one atomic per (j-run, col)
    {
      int grp = tid >> 7, c = tid & 127;
      int r0g = grp * 32;
      float accum = 0.f;
#pragma unroll 4
      for (int rr = r0g; rr < r0g + 32; ++rr) {
        accum += sT[rr * 128 + ((c + 4 * rr) & 127)];
        bool flush = (rr == r0g + 31) || (sJ[cur][rr + 1] != sJ[cur][rr]);
        if (flush) {
          unsafeAtomicAdd(A.agg + (size_t)sJ[cur][rr] * 128 + c, accum);
          accum = 0.f;
        }
      }
    }
    __syncthreads();                                   // F: T reads done before next h0
    cur ^= 1;
  }
}

// ------------------------------------------------------------ node MLP ----
__global__ __launch_bounds__(256) void node_kernel(
    const float* __restrict__ x,
    const float* __restrict__ agg_m, const float* __restrict__ agg_c,
    const short* __restrict__ WT0, const float* __restrict__ b0v,
    const short* __restrict__ WT1, const float* __restrict__ b1v,
    const short* __restrict__ WT2, const float* __restrict__ b2v,
    float* __restrict__ out) {
  __shared__ __align__(16) short sA[64 * 384];
  __shared__ float2 sP[4 * 64];
  __shared__ float2 sStats[64];
  const int tid = threadIdx.x;
  const int lane = tid & 63, wave = tid >> 6;
  const int c0 = wave * 32;
  const int n0 = blockIdx.x * 64;

#pragma unroll
  for (int p = 0; p < 3; ++p) {
    const float* src = (p == 0) ? x : (p == 1) ? agg_m : agg_c;
#pragma unroll
    for (int it = 0; it < 4; ++it) {
      int s = it * 256 + tid;
      int e = s >> 4, cl = s & 15;
      int n = n0 + e;
      f4 u0 = {0.f, 0.f, 0.f, 0.f}, u1 = {0.f, 0.f, 0.f, 0.f};
      if (n < NN) {
        u0 = *reinterpret_cast<const f4*>(src + (size_t)n * 128 + cl * 8);
        u1 = *reinterpret_cast<const f4*>(src + (size_t)n * 128 + cl * 8 + 4);
      }
      bf8 o;
#pragma unroll
      for (int j = 0; j < 4; ++j) { o[j] = f2bf(u0[j]); o[j + 4] = f2bf(u1[j]); }
      int c = p * 16 + cl;
      *reinterpret_cast<bf8*>(sA + e * 384 + ((c ^ (e & 7)) << 3)) = o;
    }
  }
  __syncthreads();

  f4 acc[4][2];
  mfma_gemm<384>(sA, 48, WT0, c0, lane, b0v, acc);
  __syncthreads();
  store_frags<true, true>(sA, 16, c0, lane, acc);
  __syncthreads();
  mfma_gemm<128>(sA, 16, WT1, c0, lane, b1v, acc);
  __syncthreads();
  store_frags<true, true>(sA + 8192, 16, c0, lane, acc);
  __syncthreads();
  mfma_gemm<128>(sA + 8192, 16, WT2, c0, lane, b2v, acc);

  ln_rows(acc, lane, wave, sP);
  __syncthreads();
  if (tid < 64) {
    float s = 0.f, qq = 0.f;
#pragma unroll
    for (int w = 0; w < 4; ++w) { s += sP[w * 64 + tid].x; qq += sP[w * 64 + tid].y; }
    float mean = s * (1.f / 128.f);
    float var = qq * (1.f / 128.f) - mean * mean;
    sStats[tid] = make_float2(mean, rsqrtf(var + 1e-5f));
  }
  __syncthreads();

#pragma unroll
  for (int rf = 0; rf < 4; ++rf)
#pragma unroll
    for (int q = 0; q < 4; ++q) {
      int row = rf * 16 + ((lane >> 4) << 2) + q;
      int n = n0 + row;
      if (n < NN) {
        float mean = sStats[row].x, rn = sStats[row].y;
#pragma unroll
        for (int cf = 0; cf < 2; ++cf) {
          int col = c0 + cf * 16 + (lane & 15);
          float xv = x[(size_t)n * 128 + col];
          out[(size_t)n * 128 + col] = (acc[rf][cf][q] - mean) * rn + xv;
        }
      }
    }
}

// -------------------------------------------------------------- launch ----
extern "C" void kernel_launch(void* const* d_in, const int* in_sizes, int n_in,
                              void* d_out, int out_size, void* d_ws, size_t ws_size,
                              hipStream_t stream) {
  const float* x   = (const float*)d_in[0];
  const int*   g   = (const int*)d_in[1];
  const int*   cgr = (const int*)d_in[2];
  const float* pp  = (const float*)d_in[3];
  const float* mW0 = (const float*)d_in[4];
  const float* mb0 = (const float*)d_in[5];
  const float* mW1 = (const float*)d_in[6];
  const float* mb1 = (const float*)d_in[7];
  const float* mW2 = (const float*)d_in[8];
  const float* mb2 = (const float*)d_in[9];
  const float* cW0 = (const float*)d_in[10];
  const float* cb0 = (const float*)d_in[11];
  const float* cW1 = (const float*)d_in[12];
  const float* cb1 = (const float*)d_in[13];
  const float* cW2 = (const float*)d_in[14];
  const float* cb2 = (const float*)d_in[15];
  const float* nW0 = (const float*)d_in[16];
  const float* nb0 = (const float*)d_in[17];
  const float* nW1 = (const float*)d_in[18];
  const float* nb1 = (const float*)d_in[19];
  const float* nW2 = (const float*)d_in[20];
  const float* nb2 = (const float*)d_in[21];
  float* out = (float*)d_out;

  // ---- weight transpose packing (compute total size FIRST) ----
  WTDesc d;
  const float* srcs[11] = {mW1, mW2, cW1, cW2, nW0, nW1, nW2,
                           mW0 + 8 * 128, mW0 + 136 * 128, cW0 + 4 * 128, cW0 + 132 * 128};
  int Ks[11] = {128, 128, 128, 128, 384, 128, 128, 128, 128, 128, 128};
  int off = 0;
  for (int m = 0; m < 11; ++m) { d.src[m] = srcs[m]; d.K[m] = Ks[m]; d.off[m] = off; off += Ks[m] * 128; }

  // ---- workspace layout ----
  char* ws = (char*)d_ws;
  const size_t TBL = (size_t)NN * 128 * 2;        // 12.8 MB (bf16 table)
  const size_t AGG = (size_t)NN * 128 * 4;        // 25.6 MB (f32 agg)
  short* xa_m = (short*)(ws);
  short* xb_m = (short*)(ws + TBL);
  short* xa_c = (short*)(ws + 2 * TBL);
  short* xb_c = (short*)(ws + 3 * TBL);
  float* agg_m = (float*)(ws + 4 * TBL);
  float* agg_c = (float*)(ws + 4 * TBL + AGG);
  short* wt = (short*)(ws + 4 * TBL + 2 * AGG);
  char* ib = ws + 4 * TBL + 2 * AGG + (size_t)off * 2;   // after FULL wt buffer
  int* hist_m   = (int*)(ib);
  int* hist_c   = hist_m + NP;
  int* cursor_m = hist_c + NP;
  int* cursor_c = cursor_m + NP;
  int* tsum_m   = cursor_c + NP;
  int* tsum_c   = tsum_m + 128;
  int* si_m     = tsum_c + 128;
  int* sj_m     = si_m + NE_MAIN;
  int* si_c     = sj_m + NE_MAIN;
  int* sj_c     = si_c + NE_CONT;

  short* wt1_m = wt + d.off[0];
  short* wt2_m = wt + d.off[1];
  short* wt1_c = wt + d.off[2];
  short* wt2_c = wt + d.off[3];
  short* wtn0  = wt + d.off[4];
  short* wtn1  = wt + d.off[5];
  short* wtn2  = wt + d.off[6];
  short* wtp   = wt + d.off[7];

  const int NT = (NN + 511) / 512;   // 98 scan tiles

  wt_kernel<<<11 * 128, 128, 0, stream>>>(d, wt);
  zero_kernel<<<2048, 256, 0, stream>>>((f4*)agg_m, (int)(2 * (size_t)NN * 128 / 4));
  zero_kernel<<<128, 256, 0, stream>>>((f4*)hist_m, 2 * NP / 4);

  // counting sort by j (both edge sets)
  hist_kernel<<<1024, 256, 0, stream>>>(g, NE_MAIN, hist_m);
  hist_kernel<<<512, 256, 0, stream>>>(cgr, NE_CONT, hist_c);
  scan1_kernel<<<NT, 512, 0, stream>>>(hist_m, cursor_m, tsum_m, NN);
  scan1_kernel<<<NT, 512, 0, stream>>>(hist_c, cursor_c, tsum_c, NN);
  scan2_kernel<<<1, 512, 0, stream>>>(tsum_m, NT);
  scan2_kernel<<<1, 512, 0, stream>>>(tsum_c, NT);
  scan3_kernel<<<NT, 512, 0, stream>>>(cursor_m, tsum_m, NN);
  scan3_kernel<<<NT, 512, 0, stream>>>(cursor_c, tsum_c, NN);
  scatter_kernel<<<1024, 256, 0, stream>>>(g, NE_MAIN, cursor_m, si_m, sj_m);
  scatter_kernel<<<512, 256, 0, stream>>>(cgr, NE_CONT, cursor_c, si_c, sj_c);

  precompute_kernel<<<(NN + 63) / 64, 256, 0, stream>>>(x, wtp, mb0, cb0,
                                                        xa_m, xb_m, xa_c, xb_c);

  EdgeArgs am = {si_m, sj_m, xa_m, xb_m, pp, mW0, wt1_m, mb1, wt2_m, mb2,
                 agg_m, NE_MAIN / 64, BLK_M, 8};
  EdgeArgs ac = {si_c, sj_c, xa_c, xb_c, pp, cW0, wt1_c, cb1, wt2_c, cb2,
                 agg_c, NE_CONT / 64, BLK_C, 4};
  edge_fused_kernel<<<BLK_M + BLK_C, 256, 0, stream>>>(am, ac, BLK_M);

  node_kernel<<<(NN + 63) / 64, 256, 0, stream>>>(x, agg_m, agg_c,
                                                  wtn0, nb0, wtn1, nb1, wtn2, nb2, out);
}